// Round 3
// baseline (874.460 us; speedup 1.0000x reference)
//
#include <hip/hip_runtime.h>
#include <stdint.h>

// ---------------------------------------------------------------------------
// FourierLayer: 5x [conv2x2s2 + BN(eval) + ReLU] -> fuse proj -> rFFT(32) ->
// gating (top-3 softmax) on MI355X.
//
// All convs are GEMMs C[M x 256] = A[M x K] * B^T. Layer0's A (im2col of the
// fp32 NCHW input, k = ci*4+q) is materialized as bf16 by a streaming
// transpose kernel (4 M-chunks, LLC-hot for the following GEMM). Layers 1-4
// read the previous layer's patch-Z output as a dense A (k = q*256+ci).
// GEMM tile: 128 rows x 256 cols (full N), BK=64, 256 thr, 48 KB LDS ->
// 2 blocks/CU for inter-block stage/compute overlap (m97 structure).
// ---------------------------------------------------------------------------

typedef __attribute__((ext_vector_type(8))) short bf16x8;
typedef __attribute__((ext_vector_type(4))) float f32x4;
typedef __attribute__((ext_vector_type(2))) long long i64x2;

#define DEV __device__ __forceinline__
#define GLOBAL_AS __attribute__((address_space(1)))
#define LDS_AS __attribute__((address_space(3)))

DEV unsigned short f2bf(float f) {
  union { float f; uint32_t u; } v; v.f = f;
  uint32_t u = v.u;
  return (unsigned short)((u + 0x7fffu + ((u >> 16) & 1u)) >> 16);
}

DEV void async16(const void* g, void* l) {
  __builtin_amdgcn_global_load_lds((GLOBAL_AS void*)g, (LDS_AS void*)l, 16, 0, 0);
}

// --------------------------- weight prep ----------------------------------
// idx < 262144: layer0 B: Bt[co][k=ci*4+q] (matches convert's A layout).
// else l=1..4:  Bt[l][co][k=q*256+ci]      (matches patch-Z A layout).
__global__ void prep_kernel(const float* __restrict__ conv_w,
                            const float* __restrict__ conv_b,
                            const float* __restrict__ gamma,
                            const float* __restrict__ beta,
                            const float* __restrict__ mean,
                            const float* __restrict__ var,
                            const float* __restrict__ fuse_w,
                            unsigned short* __restrict__ Bt_all,
                            unsigned short* __restrict__ Bt_fuse,
                            float* __restrict__ bias_all) {
  int idx = blockIdx.x * 256 + threadIdx.x;
  const int NB = 5 * 256 * 1024;
  if (idx < 262144) {
    int co = idx >> 10;
    int k = idx & 1023;
    int ci = k >> 2;
    int q = k & 3;
    float scale = gamma[co] * rsqrtf(var[co] + 1e-5f);
    float w = conv_w[(((size_t)co * 256 + ci) << 2) + q] * scale;
    Bt_all[idx] = f2bf(w);
  } else if (idx < NB) {
    int l = idx >> 18;  // 1..4
    int rem = idx & 262143;
    int co = rem >> 10;
    int k = rem & 1023;
    int q = k >> 8;
    int ci = k & 255;
    int lc = l * 256 + co;
    float scale = gamma[lc] * rsqrtf(var[lc] + 1e-5f);
    float w = conv_w[(((size_t)lc * 256 + ci) << 2) + q] * scale;
    Bt_all[idx] = f2bf(w);
  } else if (idx < NB + 65536) {
    int i = idx - NB;
    Bt_fuse[i] = f2bf(fuse_w[i]);
  } else if (idx < NB + 65536 + 1280) {
    int j = idx - (NB + 65536);
    float scale = gamma[j] * rsqrtf(var[j] + 1e-5f);
    bias_all[j] = (conv_b[j] - mean[j]) * scale + beta[j];
  }
}

// --------------------------- convert (im2col fp32 -> bf16) ------------------
// Block = (cb in [0,8), n_local in [0,64)): 32 channels x 1024 px of image
// n_ofs+n_local. Reads 128 B-coalesced; LDS transpose (u64 quads, rotated
// column = conflict-free at the data floor); writes 256 B k-segments.
// A0 row = n_local*256 + r (chunk-local), cols [cb*128, cb*128+128).
__global__ __launch_bounds__(256) void convert_kernel(
    const float* __restrict__ X, unsigned short* __restrict__ A0, int n_ofs) {
  __shared__ unsigned long long lds[8192];  // [r(256)][ci'(32)] u64 quads
  const int t = threadIdx.x;
  const int cb = blockIdx.x, nl = blockIdx.y;
  const int xp = t & 7, ci = t >> 3;  // ci in [0,32)
  const float* src =
      X + (size_t)(n_ofs + nl) * 262144 + (size_t)(cb * 32 + ci) * 1024 + xp * 4;

#pragma unroll
  for (int j2 = 0; j2 < 16; ++j2) {
    const float4 f0 = *(const float4*)(src + j2 * 64);        // Y = 2*j2
    const float4 f1 = *(const float4*)(src + j2 * 64 + 32);   // Y = 2*j2+1
    int r0 = j2 * 16 + 2 * xp;
    // quad r0: q0..q3 = f0.x f0.y f1.x f1.y ; quad r0+1: f0.z f0.w f1.z f1.w
    unsigned long long u0 =
        (unsigned long long)(((uint32_t)f2bf(f0.y) << 16) | f2bf(f0.x)) |
        ((unsigned long long)(((uint32_t)f2bf(f1.y) << 16) | f2bf(f1.x)) << 32);
    unsigned long long u1 =
        (unsigned long long)(((uint32_t)f2bf(f0.w) << 16) | f2bf(f0.z)) |
        ((unsigned long long)(((uint32_t)f2bf(f1.w) << 16) | f2bf(f1.z)) << 32);
    lds[r0 * 32 + ((ci + 2 * r0) & 31)] = u0;
    int r1 = r0 + 1;
    lds[r1 * 32 + ((ci + 2 * r1) & 31)] = u1;
  }
  __syncthreads();

  const int ci2 = t & 15;
  unsigned short* dst = A0 + ((size_t)nl * 256) * 1024 + cb * 128 + ci2 * 8;
#pragma unroll
  for (int v = 0; v < 16; ++v) {
    int r = v * 16 + (t >> 4);
    int x = (2 * ci2 + 2 * r) & 31;  // even -> pair contiguous, 16B aligned
    i64x2 val = *(const i64x2*)&lds[r * 32 + x];
    *(i64x2*)(dst + (size_t)r * 1024) = val;
  }
}

// --------------------------- generic GEMM ----------------------------------
// C[M x 256] = A[M x K] * Bt[256 x K]^T + bias. Tile 128 x 256 (full N),
// BK=64, 256 thr (4 waves: 2r x 2c of 64x128). XOR-8 swizzle on 16B units.
template <bool OUT_F32, bool RELU>
__global__ __launch_bounds__(256) void gemm_kernel(
    const unsigned short* __restrict__ A, const unsigned short* __restrict__ Bt,
    const float* __restrict__ bias, void* __restrict__ Out, int K,
    int hw_shift, int wsh, int hw1, int Roff) {
  __shared__ __align__(16) unsigned short As[128 * 64];
  __shared__ __align__(16) unsigned short Bs[256 * 64];
  const int t = threadIdx.x;
  const int lane = t & 63, wave = t >> 6;
  const int R0 = blockIdx.x * 128;
  const int rw = wave >> 1, cw = wave & 1;
  const int m16 = lane & 15, quad = lane >> 4;

  const unsigned short* ga[4];
  const unsigned short* gb[8];
#pragma unroll
  for (int p = 0; p < 4; ++p) {
    int g = p * 256 + t;
    int r = g >> 3, u = g & 7;
    ga[p] = A + (size_t)(R0 + r) * K + ((u ^ (r & 7)) << 3);
  }
#pragma unroll
  for (int p = 0; p < 8; ++p) {
    int g = p * 256 + t;
    int r = g >> 3, u = g & 7;
    gb[p] = Bt + (size_t)r * K + ((u ^ (r & 7)) << 3);
  }

  const f32x4 zero = {0.f, 0.f, 0.f, 0.f};
  f32x4 acc[4][8];
#pragma unroll
  for (int i = 0; i < 4; ++i)
#pragma unroll
    for (int j = 0; j < 8; ++j) acc[i][j] = zero;

  const int kIters = K >> 6;
  for (int kt = 0; kt < kIters; ++kt) {
#pragma unroll
    for (int p = 0; p < 4; ++p) {
      async16(ga[p], &As[(p * 256 + t) * 8]);
      ga[p] += 64;
    }
#pragma unroll
    for (int p = 0; p < 8; ++p) {
      async16(gb[p], &Bs[(p * 256 + t) * 8]);
      gb[p] += 64;
    }
    __syncthreads();
#pragma unroll
    for (int ks = 0; ks < 2; ++ks) {
      bf16x8 af[4], bfr[8];
      int ul = (ks << 2) + quad;
#pragma unroll
      for (int f = 0; f < 4; ++f) {
        int ra = rw * 64 + f * 16 + m16;
        af[f] = *(const bf16x8*)&As[ra * 64 + ((ul ^ (ra & 7)) << 3)];
      }
#pragma unroll
      for (int f = 0; f < 8; ++f) {
        int rb = cw * 128 + f * 16 + m16;
        bfr[f] = *(const bf16x8*)&Bs[rb * 64 + ((ul ^ (rb & 7)) << 3)];
      }
#pragma unroll
      for (int fi = 0; fi < 4; ++fi)
#pragma unroll
        for (int fj = 0; fj < 8; ++fj)
          acc[fi][fj] = __builtin_amdgcn_mfma_f32_16x16x32_bf16(
              af[fi], bfr[fj], acc[fi][fj], 0, 0, 0);
    }
    __syncthreads();
  }

  float biasv[8];
#pragma unroll
  for (int fj = 0; fj < 8; ++fj) biasv[fj] = bias[cw * 128 + fj * 16 + m16];

#pragma unroll
  for (int fi = 0; fi < 4; ++fi) {
#pragma unroll
    for (int fj = 0; fj < 8; ++fj) {
      int col = cw * 128 + fj * 16 + m16;
      f32x4 v = acc[fi][fj];
#pragma unroll
      for (int i = 0; i < 4; ++i) {
        int R = Roff + R0 + rw * 64 + fi * 16 + quad * 4 + i;
        float val = v[i] + biasv[fj];
        if (RELU) val = fmaxf(val, 0.f);
        size_t addr;
        if (hw1) {
          addr = ((size_t)R << 8) + col;
        } else {
          int n = R >> hw_shift;
          int rem = R & ((1 << hw_shift) - 1);
          int y = rem >> wsh;
          int x = rem & ((1 << wsh) - 1);
          int q = ((y & 1) << 1) | (x & 1);
          addr = ((size_t)n << (hw_shift + 8)) + ((size_t)(y >> 1) << (wsh + 9)) +
                 ((size_t)(x >> 1) << 10) + (q << 8) + col;
        }
        if (OUT_F32)
          ((float*)Out)[addr] = val;
        else
          ((unsigned short*)Out)[addr] = f2bf(val);
      }
    }
  }
}

// --------------------------- FFT + gate logits ------------------------------
__global__ void fft_gate_kernel(const float* __restrict__ hbuf,
                                const float* __restrict__ w_gate,
                                float* __restrict__ weights) {
  __shared__ float cs[32], sn[32];
  __shared__ float wg[144];
  __shared__ float red[4][9];
  const int b = blockIdx.x, t = threadIdx.x;
  if (t < 32) {
    float ang = 6.283185307179586f * (float)t / 32.0f;
    cs[t] = cosf(ang);
    sn[t] = sinf(ang);
  }
  if (t < 144) wg[t] = w_gate[t];
  __syncthreads();

  float hl[32];
#pragma unroll
  for (int tt = 0; tt < 32; ++tt) hl[tt] = hbuf[(size_t)(b * 32 + tt) * 256 + t];

  float lg[9];
#pragma unroll
  for (int s = 0; s < 9; ++s) lg[s] = 0.f;

#pragma unroll
  for (int f = 1; f <= 16; ++f) {
    float re = 0.f, im = 0.f;
#pragma unroll
    for (int tt = 0; tt < 32; ++tt) {
      int idx = (f * tt) & 31;
      re += hl[tt] * cs[idx];
      im += hl[tt] * sn[idx];
    }
    float amp = sqrtf(re * re + im * im) * 0.17677669529663687f;  // 1/sqrt(32)
#pragma unroll
    for (int s = 0; s < 9; ++s) lg[s] += amp * wg[(f - 1) * 9 + s];
  }

  const int lane = t & 63, wave = t >> 6;
#pragma unroll
  for (int s = 0; s < 9; ++s) {
    float v = lg[s];
    v += __shfl_down(v, 32, 64);
    v += __shfl_down(v, 16, 64);
    v += __shfl_down(v, 8, 64);
    v += __shfl_down(v, 4, 64);
    v += __shfl_down(v, 2, 64);
    v += __shfl_down(v, 1, 64);
    if (lane == 0) red[wave][s] = v;
  }
  __syncthreads();
  if (t < 9) {
    float total = red[0][t] + red[1][t] + red[2][t] + red[3][t];
    weights[b * 9 + t] = total * (1.0f / 256.0f);
  }
}

// --------------------------- finalize: top-k gates + load -------------------
__global__ void finalize_kernel(const float* __restrict__ weights,
                                float* __restrict__ out) {
  const int t = threadIdx.x;
  if (t < 8) {
    float w[9];
    int idx[9];
#pragma unroll
    for (int s = 0; s < 9; ++s) {
      w[s] = weights[t * 9 + s];
      idx[s] = s;
    }
    for (int a = 0; a < 4; ++a) {
      int best = a;
      for (int c = a + 1; c < 9; ++c)
        if (w[idx[c]] > w[idx[best]]) best = c;
      int tmp = idx[a];
      idx[a] = idx[best];
      idx[best] = tmp;
    }
    float m = w[idx[0]];
    float e0 = expf(w[idx[0]] - m);
    float e1 = expf(w[idx[1]] - m);
    float e2 = expf(w[idx[2]] - m);
    float inv = 1.0f / (e0 + e1 + e2);
    float g[9];
#pragma unroll
    for (int s = 0; s < 9; ++s) g[s] = 0.f;
    g[idx[0]] = e0 * inv;
    g[idx[1]] = e1 * inv;
    g[idx[2]] = e2 * inv;
#pragma unroll
    for (int s = 0; s < 9; ++s) out[t * 9 + s] = g[s];
  }
  __syncthreads();
  if (t < 9) {
    int cnt = 0;
#pragma unroll
    for (int b = 0; b < 8; ++b) cnt += (out[b * 9 + t] > 0.f) ? 1 : 0;
    out[72 + t] = (float)cnt;
  }
}

// --------------------------- launch ----------------------------------------
extern "C" void kernel_launch(void* const* d_in, const int* in_sizes, int n_in,
                              void* d_out, int out_size, void* d_ws,
                              size_t ws_size, hipStream_t stream) {
  (void)in_sizes; (void)n_in; (void)out_size; (void)ws_size;
  const float* x      = (const float*)d_in[0];
  const float* conv_w = (const float*)d_in[1];
  const float* conv_b = (const float*)d_in[2];
  const float* gamma  = (const float*)d_in[3];
  const float* beta   = (const float*)d_in[4];
  const float* mean   = (const float*)d_in[5];
  const float* var    = (const float*)d_in[6];
  const float* fuse_w = (const float*)d_in[7];
  const float* fuse_b = (const float*)d_in[8];
  const float* w_gate = (const float*)d_in[9];

  char* ws = (char*)d_ws;
  size_t off = 0;
  auto alloc = [&](size_t bytes) {
    void* p = ws + off;
    off = (off + bytes + 255) & ~(size_t)255;
    return p;
  };
  unsigned short* Bt_all  = (unsigned short*)alloc((size_t)5 * 262144 * 2);
  unsigned short* Bt_fuse = (unsigned short*)alloc((size_t)65536 * 2);
  float* bias_all         = (float*)alloc(1280 * 4);
  unsigned short* A0c     = (unsigned short*)alloc((size_t)16384 * 1024 * 2);
  unsigned short* inter0  = (unsigned short*)alloc((size_t)65536 * 256 * 2);
  unsigned short* inter1  = (unsigned short*)alloc((size_t)16384 * 256 * 2);
  unsigned short* inter2  = (unsigned short*)alloc((size_t)4096 * 256 * 2);
  unsigned short* inter3  = (unsigned short*)alloc((size_t)1024 * 256 * 2);
  unsigned short* inter4  = (unsigned short*)alloc((size_t)256 * 256 * 2);
  float* hbuf             = (float*)alloc((size_t)256 * 256 * 4);
  float* wts              = (float*)alloc(72 * 4);

  prep_kernel<<<5381, 256, 0, stream>>>(conv_w, conv_b, gamma, beta, mean, var,
                                        fuse_w, Bt_all, Bt_fuse, bias_all);
  // layer0 in 4 M-chunks of 64 images: convert (fp32->bf16 im2col) then GEMM
  for (int c = 0; c < 4; ++c) {
    convert_kernel<<<dim3(8, 64), 256, 0, stream>>>(x, A0c, c * 64);
    gemm_kernel<false, true><<<128, 256, 0, stream>>>(
        A0c, Bt_all, bias_all, inter0, 1024, 8, 4, 0, c * 16384);
  }
  gemm_kernel<false, true><<<128, 256, 0, stream>>>(
      inter0, Bt_all + 262144, bias_all + 256, inter1, 1024, 6, 3, 0, 0);
  gemm_kernel<false, true><<<32, 256, 0, stream>>>(
      inter1, Bt_all + 2 * 262144, bias_all + 512, inter2, 1024, 4, 2, 0, 0);
  gemm_kernel<false, true><<<8, 256, 0, stream>>>(
      inter2, Bt_all + 3 * 262144, bias_all + 768, inter3, 1024, 2, 1, 0, 0);
  gemm_kernel<false, true><<<2, 256, 0, stream>>>(
      inter3, Bt_all + 4 * 262144, bias_all + 1024, inter4, 1024, 0, 0, 1, 0);
  gemm_kernel<true, false><<<2, 256, 0, stream>>>(
      inter4, Bt_fuse, fuse_b, hbuf, 256, 0, 0, 1, 0);
  fft_gate_kernel<<<8, 256, 0, stream>>>(hbuf, w_gate, wts);
  finalize_kernel<<<1, 64, 0, stream>>>(wts, (float*)d_out);
}

// Round 4
// 571.665 us; speedup vs baseline: 1.5297x; 1.5297x over previous
//
#include <hip/hip_runtime.h>
#include <stdint.h>

// ---------------------------------------------------------------------------
// FourierLayer: 5x [conv2x2s2 + BN(eval) + ReLU] -> fuse proj -> rFFT(32) ->
// gating (top-3 softmax) on MI355X.
//
// All convs are GEMMs C[M x 256] = A[M x K] * B^T. Layer0 fuses the im2col of
// the fp32 NCHW input: one block per half-image (grid 512), tile 128 rows x
// 256 cols, BK=64 (16 ci x 4 q). A is staged reg-path fp32->bf16 with
// per-lane-varying ci + row-rotation swizzle (round-2 pattern, measured 0 bank
// conflicts); B staged via contiguous global_load_lds from a prep-transposed
// [kt][u][c][kv] image. Layers 1-4 read patch-Z outputs as dense A
// (k = q*256+ci):
//   addr(n,y,x,co) = n*(h*w*256) + (y>>1)*(w/2)*1024 + (x>>1)*1024
//                    + ((y&1)*2+(x&1))*256 + co
// __launch_bounds__(256,2) everywhere: cap VGPR<=256 -> 2 blocks/CU overlap.
// ---------------------------------------------------------------------------

typedef __attribute__((ext_vector_type(8))) short bf16x8;
typedef __attribute__((ext_vector_type(4))) float f32x4;

#define DEV __device__ __forceinline__
#define GLOBAL_AS __attribute__((address_space(1)))
#define LDS_AS __attribute__((address_space(3)))

DEV unsigned short f2bf(float f) {
  union { float f; uint32_t u; } v; v.f = f;
  uint32_t u = v.u;
  return (unsigned short)((u + 0x7fffu + ((u >> 16) & 1u)) >> 16);
}

DEV void async16(const void* g, void* l) {
  __builtin_amdgcn_global_load_lds((GLOBAL_AS void*)g, (LDS_AS void*)l, 16, 0, 0);
}

// --------------------------- weight prep ----------------------------------
// idx < 262144: layer0 B image [kt(16)][u(8)][c(256)][kv(8)], k=q*16+ci_l,
//               u=k>>3 (q=u>>1, ci_l=(u&1)*8+kv), ci=kt*16+ci_l.
// else l=1..4:  Bt[l][co][k=q*256+ci] (patch-Z A order). Then Bt_fuse, bias.
__global__ void prep_kernel(const float* __restrict__ conv_w,
                            const float* __restrict__ conv_b,
                            const float* __restrict__ gamma,
                            const float* __restrict__ beta,
                            const float* __restrict__ mean,
                            const float* __restrict__ var,
                            const float* __restrict__ fuse_w,
                            unsigned short* __restrict__ Bt_all,
                            unsigned short* __restrict__ Bt_fuse,
                            float* __restrict__ bias_all) {
  int idx = blockIdx.x * 256 + threadIdx.x;
  const int NB = 5 * 256 * 1024;
  if (idx < 262144) {
    int kv = idx & 7;
    int c = (idx >> 3) & 255;
    int u = (idx >> 11) & 7;
    int kt = idx >> 14;
    int q = u >> 1;
    int ci = kt * 16 + (u & 1) * 8 + kv;
    float scale = gamma[c] * rsqrtf(var[c] + 1e-5f);
    Bt_all[idx] = f2bf(conv_w[(((size_t)c * 256 + ci) << 2) + q] * scale);
  } else if (idx < NB) {
    int l = idx >> 18;  // 1..4
    int rem = idx & 262143;
    int co = rem >> 10;
    int k = rem & 1023;
    int q = k >> 8;
    int ci = k & 255;
    int lc = l * 256 + co;
    float scale = gamma[lc] * rsqrtf(var[lc] + 1e-5f);
    Bt_all[idx] = f2bf(conv_w[(((size_t)lc * 256 + ci) << 2) + q] * scale);
  } else if (idx < NB + 65536) {
    int i = idx - NB;
    Bt_fuse[i] = f2bf(fuse_w[i]);
  } else if (idx < NB + 65536 + 1280) {
    int j = idx - (NB + 65536);
    float scale = gamma[j] * rsqrtf(var[j] + 1e-5f);
    bias_all[j] = (conv_b[j] - mean[j]) * scale + beta[j];
  }
}

// --------------------------- layer 0 (fused im2col GEMM) --------------------
// Block = (n = blk>>1, yh = blk&1): rows r = (Yl>>1)*16 + xp, Yl in [0,16),
// Y_img = yh*16 + Yl. K-tile kt: ci in [kt*16, kt*16+16), all 4 q.
// As: [u(8)][rsw(128)][kv(8)] bf16, rsw = (r&0x78)|((r^(r>>3))&7).
// Bs: [u(8)][c(256)][kv(8)] bf16, staged contiguously via async16.
__global__ __launch_bounds__(256, 2) void layer0_kernel(
    const float* __restrict__ X, const unsigned short* __restrict__ Bt0,
    const float* __restrict__ bias, unsigned short* __restrict__ Out) {
  __shared__ __align__(16) unsigned short As[8192];
  __shared__ __align__(16) unsigned short Bs[16384];
  const int t = threadIdx.x;
  const int lane = t & 63, wave = t >> 6;
  const int n = blockIdx.x >> 1, yh = blockIdx.x & 1;
  const int m16 = lane & 15, quad = lane >> 4;
  const int rw = wave >> 1, cw = wave & 1;
  const int xq = lane & 7, ci_lo = lane >> 3;  // ci varies within wave
  const float* xn = X + (size_t)n * 262144 + (size_t)(yh * 16) * 32;

  const f32x4 zero = {0.f, 0.f, 0.f, 0.f};
  f32x4 acc[4][8];
#pragma unroll
  for (int i = 0; i < 4; ++i)
#pragma unroll
    for (int j = 0; j < 8; ++j) acc[i][j] = zero;

  for (int kt = 0; kt < 16; ++kt) {
    // B stage: 32 KB contiguous
#pragma unroll
    for (int i = 0; i < 8; ++i)
      async16(Bt0 + (size_t)kt * 16384 + (i * 256 + t) * 8,
              &Bs[(i * 256 + t) * 8]);
    // A stage: 8 float4 loads -> 32 bf16 scattered writes
#pragma unroll
    for (int j = 0; j < 8; ++j) {
      int Yl = wave * 4 + (j & 3);
      int ci_l = (j >> 2) * 8 + ci_lo;
      int ci = kt * 16 + ci_l;
      const float4 f = *(const float4*)(xn + (size_t)ci * 1024 + Yl * 32 + xq * 4);
      int qY = (Yl & 1) * 2;
      int rb = (Yl >> 1) * 16 + xq * 2;
      int cihi = ci_l >> 3, kv = ci_l & 7;
      int u0 = qY * 2 + cihi;
      int r0s = (rb & 0x78) | ((rb ^ (rb >> 3)) & 7);
      int r1 = rb + 1;
      int r1s = (r1 & 0x78) | ((r1 ^ (r1 >> 3)) & 7);
      As[u0 * 1024 + r0s * 8 + kv] = f2bf(f.x);
      As[(u0 + 2) * 1024 + r0s * 8 + kv] = f2bf(f.y);
      As[u0 * 1024 + r1s * 8 + kv] = f2bf(f.z);
      As[(u0 + 2) * 1024 + r1s * 8 + kv] = f2bf(f.w);
    }
    __syncthreads();  // drains async16 (vmcnt) + ds writes
#pragma unroll
    for (int ks = 0; ks < 2; ++ks) {
      bf16x8 af[4], bfr[8];
      int ul = ks * 4 + quad;
#pragma unroll
      for (int f = 0; f < 4; ++f) {
        int r = rw * 64 + f * 16 + m16;
        int rs = (r & 0x78) | ((r ^ (r >> 3)) & 7);
        af[f] = *(const bf16x8*)&As[ul * 1024 + rs * 8];
      }
#pragma unroll
      for (int f = 0; f < 8; ++f) {
        int c = cw * 128 + f * 16 + m16;
        bfr[f] = *(const bf16x8*)&Bs[(ul * 256 + c) * 8];
      }
#pragma unroll
      for (int fi = 0; fi < 4; ++fi)
#pragma unroll
        for (int fj = 0; fj < 8; ++fj)
          acc[fi][fj] = __builtin_amdgcn_mfma_f32_16x16x32_bf16(
              af[fi], bfr[fj], acc[fi][fj], 0, 0, 0);
    }
    __syncthreads();  // LDS free for next tile's writes
  }

  float biasv[8];
#pragma unroll
  for (int fj = 0; fj < 8; ++fj) biasv[fj] = bias[cw * 128 + fj * 16 + m16];

#pragma unroll
  for (int fi = 0; fi < 4; ++fi) {
#pragma unroll
    for (int fj = 0; fj < 8; ++fj) {
      int col = cw * 128 + fj * 16 + m16;
      f32x4 v = acc[fi][fj];
#pragma unroll
      for (int i = 0; i < 4; ++i) {
        int rt = rw * 64 + fi * 16 + quad * 4 + i;
        int yo = yh * 8 + (rt >> 4);  // output pixel (16x16 grid)
        int xo = rt & 15;
        float val = fmaxf(v[i] + biasv[fj], 0.f);
        size_t addr = ((size_t)n << 16) + ((size_t)(yo >> 1) << 13) +
                      ((size_t)(xo >> 1) << 10) +
                      ((((yo & 1) << 1) | (xo & 1)) << 8) + col;
        Out[addr] = f2bf(val);
      }
    }
  }
}

// --------------------------- generic GEMM ----------------------------------
// C[M x 256] = A[M x K] * Bt[256 x K]^T + bias. Tile 128 x 256 (full N),
// BK=64, 256 thr (4 waves: 2r x 2c of 64x128). XOR-8 swizzle on 16B units.
template <bool OUT_F32, bool RELU>
__global__ __launch_bounds__(256, 2) void gemm_kernel(
    const unsigned short* __restrict__ A, const unsigned short* __restrict__ Bt,
    const float* __restrict__ bias, void* __restrict__ Out, int K,
    int hw_shift, int wsh, int hw1) {
  __shared__ __align__(16) unsigned short As[128 * 64];
  __shared__ __align__(16) unsigned short Bs[256 * 64];
  const int t = threadIdx.x;
  const int lane = t & 63, wave = t >> 6;
  const int R0 = blockIdx.x * 128;
  const int rw = wave >> 1, cw = wave & 1;
  const int m16 = lane & 15, quad = lane >> 4;

  const unsigned short* ga[4];
  const unsigned short* gb[8];
#pragma unroll
  for (int p = 0; p < 4; ++p) {
    int g = p * 256 + t;
    int r = g >> 3, u = g & 7;
    ga[p] = A + (size_t)(R0 + r) * K + ((u ^ (r & 7)) << 3);
  }
#pragma unroll
  for (int p = 0; p < 8; ++p) {
    int g = p * 256 + t;
    int r = g >> 3, u = g & 7;
    gb[p] = Bt + (size_t)r * K + ((u ^ (r & 7)) << 3);
  }

  const f32x4 zero = {0.f, 0.f, 0.f, 0.f};
  f32x4 acc[4][8];
#pragma unroll
  for (int i = 0; i < 4; ++i)
#pragma unroll
    for (int j = 0; j < 8; ++j) acc[i][j] = zero;

  const int kIters = K >> 6;
  for (int kt = 0; kt < kIters; ++kt) {
#pragma unroll
    for (int p = 0; p < 4; ++p) {
      async16(ga[p], &As[(p * 256 + t) * 8]);
      ga[p] += 64;
    }
#pragma unroll
    for (int p = 0; p < 8; ++p) {
      async16(gb[p], &Bs[(p * 256 + t) * 8]);
      gb[p] += 64;
    }
    __syncthreads();
#pragma unroll
    for (int ks = 0; ks < 2; ++ks) {
      bf16x8 af[4], bfr[8];
      int ul = (ks << 2) + quad;
#pragma unroll
      for (int f = 0; f < 4; ++f) {
        int ra = rw * 64 + f * 16 + m16;
        af[f] = *(const bf16x8*)&As[ra * 64 + ((ul ^ (ra & 7)) << 3)];
      }
#pragma unroll
      for (int f = 0; f < 8; ++f) {
        int rb = cw * 128 + f * 16 + m16;
        bfr[f] = *(const bf16x8*)&Bs[rb * 64 + ((ul ^ (rb & 7)) << 3)];
      }
#pragma unroll
      for (int fi = 0; fi < 4; ++fi)
#pragma unroll
        for (int fj = 0; fj < 8; ++fj)
          acc[fi][fj] = __builtin_amdgcn_mfma_f32_16x16x32_bf16(
              af[fi], bfr[fj], acc[fi][fj], 0, 0, 0);
    }
    __syncthreads();
  }

  float biasv[8];
#pragma unroll
  for (int fj = 0; fj < 8; ++fj) biasv[fj] = bias[cw * 128 + fj * 16 + m16];

#pragma unroll
  for (int fi = 0; fi < 4; ++fi) {
#pragma unroll
    for (int fj = 0; fj < 8; ++fj) {
      int col = cw * 128 + fj * 16 + m16;
      f32x4 v = acc[fi][fj];
#pragma unroll
      for (int i = 0; i < 4; ++i) {
        int R = R0 + rw * 64 + fi * 16 + quad * 4 + i;
        float val = v[i] + biasv[fj];
        if (RELU) val = fmaxf(val, 0.f);
        size_t addr;
        if (hw1) {
          addr = ((size_t)R << 8) + col;
        } else {
          int n = R >> hw_shift;
          int rem = R & ((1 << hw_shift) - 1);
          int y = rem >> wsh;
          int x = rem & ((1 << wsh) - 1);
          int q = ((y & 1) << 1) | (x & 1);
          addr = ((size_t)n << (hw_shift + 8)) + ((size_t)(y >> 1) << (wsh + 9)) +
                 ((size_t)(x >> 1) << 10) + (q << 8) + col;
        }
        if (OUT_F32)
          ((float*)Out)[addr] = val;
        else
          ((unsigned short*)Out)[addr] = f2bf(val);
      }
    }
  }
}

// --------------------------- FFT + gate logits ------------------------------
__global__ void fft_gate_kernel(const float* __restrict__ hbuf,
                                const float* __restrict__ w_gate,
                                float* __restrict__ weights) {
  __shared__ float cs[32], sn[32];
  __shared__ float wg[144];
  __shared__ float red[4][9];
  const int b = blockIdx.x, t = threadIdx.x;
  if (t < 32) {
    float ang = 6.283185307179586f * (float)t / 32.0f;
    cs[t] = cosf(ang);
    sn[t] = sinf(ang);
  }
  if (t < 144) wg[t] = w_gate[t];
  __syncthreads();

  float hl[32];
#pragma unroll
  for (int tt = 0; tt < 32; ++tt) hl[tt] = hbuf[(size_t)(b * 32 + tt) * 256 + t];

  float lg[9];
#pragma unroll
  for (int s = 0; s < 9; ++s) lg[s] = 0.f;

#pragma unroll
  for (int f = 1; f <= 16; ++f) {
    float re = 0.f, im = 0.f;
#pragma unroll
    for (int tt = 0; tt < 32; ++tt) {
      int idx = (f * tt) & 31;
      re += hl[tt] * cs[idx];
      im += hl[tt] * sn[idx];
    }
    float amp = sqrtf(re * re + im * im) * 0.17677669529663687f;  // 1/sqrt(32)
#pragma unroll
    for (int s = 0; s < 9; ++s) lg[s] += amp * wg[(f - 1) * 9 + s];
  }

  const int lane = t & 63, wave = t >> 6;
#pragma unroll
  for (int s = 0; s < 9; ++s) {
    float v = lg[s];
    v += __shfl_down(v, 32, 64);
    v += __shfl_down(v, 16, 64);
    v += __shfl_down(v, 8, 64);
    v += __shfl_down(v, 4, 64);
    v += __shfl_down(v, 2, 64);
    v += __shfl_down(v, 1, 64);
    if (lane == 0) red[wave][s] = v;
  }
  __syncthreads();
  if (t < 9) {
    float total = red[0][t] + red[1][t] + red[2][t] + red[3][t];
    weights[b * 9 + t] = total * (1.0f / 256.0f);
  }
}

// --------------------------- finalize: top-k gates + load -------------------
__global__ void finalize_kernel(const float* __restrict__ weights,
                                float* __restrict__ out) {
  const int t = threadIdx.x;
  if (t < 8) {
    float w[9];
    int idx[9];
#pragma unroll
    for (int s = 0; s < 9; ++s) {
      w[s] = weights[t * 9 + s];
      idx[s] = s;
    }
    for (int a = 0; a < 4; ++a) {
      int best = a;
      for (int c = a + 1; c < 9; ++c)
        if (w[idx[c]] > w[idx[best]]) best = c;
      int tmp = idx[a];
      idx[a] = idx[best];
      idx[best] = tmp;
    }
    float m = w[idx[0]];
    float e0 = expf(w[idx[0]] - m);
    float e1 = expf(w[idx[1]] - m);
    float e2 = expf(w[idx[2]] - m);
    float inv = 1.0f / (e0 + e1 + e2);
    float g[9];
#pragma unroll
    for (int s = 0; s < 9; ++s) g[s] = 0.f;
    g[idx[0]] = e0 * inv;
    g[idx[1]] = e1 * inv;
    g[idx[2]] = e2 * inv;
#pragma unroll
    for (int s = 0; s < 9; ++s) out[t * 9 + s] = g[s];
  }
  __syncthreads();
  if (t < 9) {
    int cnt = 0;
#pragma unroll
    for (int b = 0; b < 8; ++b) cnt += (out[b * 9 + t] > 0.f) ? 1 : 0;
    out[72 + t] = (float)cnt;
  }
}

// --------------------------- launch ----------------------------------------
extern "C" void kernel_launch(void* const* d_in, const int* in_sizes, int n_in,
                              void* d_out, int out_size, void* d_ws,
                              size_t ws_size, hipStream_t stream) {
  (void)in_sizes; (void)n_in; (void)out_size; (void)ws_size;
  const float* x      = (const float*)d_in[0];
  const float* conv_w = (const float*)d_in[1];
  const float* conv_b = (const float*)d_in[2];
  const float* gamma  = (const float*)d_in[3];
  const float* beta   = (const float*)d_in[4];
  const float* mean   = (const float*)d_in[5];
  const float* var    = (const float*)d_in[6];
  const float* fuse_w = (const float*)d_in[7];
  const float* fuse_b = (const float*)d_in[8];
  const float* w_gate = (const float*)d_in[9];

  char* ws = (char*)d_ws;
  size_t off = 0;
  auto alloc = [&](size_t bytes) {
    void* p = ws + off;
    off = (off + bytes + 255) & ~(size_t)255;
    return p;
  };
  unsigned short* Bt_all  = (unsigned short*)alloc((size_t)5 * 262144 * 2);
  unsigned short* Bt_fuse = (unsigned short*)alloc((size_t)65536 * 2);
  float* bias_all         = (float*)alloc(1280 * 4);
  unsigned short* inter0  = (unsigned short*)alloc((size_t)65536 * 256 * 2);
  unsigned short* inter1  = (unsigned short*)alloc((size_t)16384 * 256 * 2);
  unsigned short* inter2  = (unsigned short*)alloc((size_t)4096 * 256 * 2);
  unsigned short* inter3  = (unsigned short*)alloc((size_t)1024 * 256 * 2);
  unsigned short* inter4  = (unsigned short*)alloc((size_t)256 * 256 * 2);
  float* hbuf             = (float*)alloc((size_t)256 * 256 * 4);
  float* wts              = (float*)alloc(72 * 4);

  prep_kernel<<<5381, 256, 0, stream>>>(conv_w, conv_b, gamma, beta, mean, var,
                                        fuse_w, Bt_all, Bt_fuse, bias_all);
  layer0_kernel<<<512, 256, 0, stream>>>(x, Bt_all, bias_all, inter0);
  gemm_kernel<false, true><<<128, 256, 0, stream>>>(
      inter0, Bt_all + 262144, bias_all + 256, inter1, 1024, 6, 3, 0);
  gemm_kernel<false, true><<<32, 256, 0, stream>>>(
      inter1, Bt_all + 2 * 262144, bias_all + 512, inter2, 1024, 4, 2, 0);
  gemm_kernel<false, true><<<8, 256, 0, stream>>>(
      inter2, Bt_all + 3 * 262144, bias_all + 768, inter3, 1024, 2, 1, 0);
  gemm_kernel<false, true><<<2, 256, 0, stream>>>(
      inter3, Bt_all + 4 * 262144, bias_all + 1024, inter4, 1024, 0, 0, 1);
  gemm_kernel<true, false><<<2, 256, 0, stream>>>(
      inter4, Bt_fuse, fuse_b, hbuf, 256, 0, 0, 1);
  fft_gate_kernel<<<8, 256, 0, stream>>>(hbuf, w_gate, wts);
  finalize_kernel<<<1, 64, 0, stream>>>(wts, (float*)d_out);
}